// Round 2
// baseline (25429.482 us; speedup 1.0000x reference)
//
#include <hip/hip_runtime.h>
#include <math.h>

// Persistent-kernel LSTM: H=2048, SEQ=4096, fp32 (no fp32 MFMA on CDNA4 ->
// vector ALU). 256 WGs x 256 thr, 1 WG/CU. Each lane holds 8 rows x 32 cols
// of W_hh in VGPRs (64 float4 = 256 VGPRs) for the whole sequence.
// Per step: poll h_{t-1} (data-as-flag 8B atomic pairs, agent scope, tag =
// step), compute y_{t-1} in-kernel (WG0 writes it), stage h to LDS, 256
// FMAs/lane, 64-lane butterfly, gates, publish h_t slice.
// d_ws usage: 32 KB only (hbuf double buffer).

#define HDIM 2048
#define SEQ 4096
#define NWG 256
#define TPB 256

__device__ __forceinline__ float sigmoidf_(float x) {
  return 1.0f / (1.0f + expf(-x));
}
__device__ __forceinline__ float tanh_(float x) {
  float e = expf(-2.0f * fabsf(x));
  float r = (1.0f - e) / (1.0f + e);
  return copysignf(r, x);
}

__global__ void lstm_init(unsigned long long* hbuf) {
  const int i = blockIdx.x * 256 + threadIdx.x;   // 2048 threads
  hbuf[HDIM + i] = 0ull;  // slot 1 = h_{-1}: value 0.0f, tag 0
}

__global__ __launch_bounds__(TPB, 1) void lstm_persist(
    const float* __restrict__ x, const float* __restrict__ w_ih,
    const float* __restrict__ w_hh, const float* __restrict__ b_ih,
    const float* __restrict__ b_hh, const float* __restrict__ w_out,
    const float* __restrict__ b_out, float* __restrict__ out,
    unsigned long long* hbuf)
{
  const int wg   = blockIdx.x;
  const int tid  = threadIdx.x;
  const int wave = tid >> 6;
  const int lane = tid & 63;
  const int k0   = wg * 8 + wave * 2;   // this wave owns hidden units k0,k0+1
  const int k1   = k0 + 1;

  __shared__ float xs[SEQ];     // 16 KB: whole input sequence
  __shared__ float hs[HDIM];    // 8 KB: staged h_{t-1}
  __shared__ float wys[4];      // per-wave y partials

  // ---- one-time: weights into registers ----
  // rows m=0..7: gates (i,f,g,o) of unit k0 then k1:
  //   row = k0 + (m>>2) + (m&3)*HDIM
  // cols per lane: {256*j + 4*lane + q}, j=0..7, q=0..3
  float4 W[64];
  float wx[8], bb[8];
  #pragma unroll
  for (int m = 0; m < 8; ++m) {
    const int row = k0 + (m >> 2) + (m & 3) * HDIM;
    const float* rp = w_hh + (size_t)row * HDIM + lane * 4;
    #pragma unroll
    for (int j = 0; j < 8; ++j)
      W[m * 8 + j] = *(const float4*)(rp + j * 256);
    wx[m] = w_ih[row];
    bb[m] = b_ih[row] + b_hh[row];
  }
  const float wo0 = w_out[k0], wo1 = w_out[k1];
  float wo[8];
  #pragma unroll
  for (int q = 0; q < 8; ++q) wo[q] = w_out[tid + 256 * q];
  const float bout = b_out[0];

  for (int i = tid; i < SEQ; i += TPB) xs[i] = x[i];
  (void)wo0; (void)wo1;

  float c0 = 0.f, c1 = 0.f, h0 = 0.f, h1 = 0.f;
  __syncthreads();

  for (int t = 0; t <= SEQ; ++t) {
    // ---- poll h_{t-1}: pairs (tag,val), want tag == t; slot (t-1)&1 ----
    unsigned long long* src = hbuf + ((((unsigned)t & 1u) ^ 1u) * HDIM);
    unsigned long long p[8];
    float hv[8];
    #pragma unroll
    for (int q = 0; q < 8; ++q) hv[q] = 0.f;
    unsigned mask = 0xFFu;
    int guard = 0;
    while (mask) {
      #pragma unroll
      for (int q = 0; q < 8; ++q)
        if (mask & (1u << q))
          p[q] = __hip_atomic_load(&src[tid + 256 * q], __ATOMIC_RELAXED,
                                   __HIP_MEMORY_SCOPE_AGENT);
      #pragma unroll
      for (int q = 0; q < 8; ++q)
        if ((mask & (1u << q)) && (unsigned)(p[q] >> 32) == (unsigned)t) {
          hv[q] = __uint_as_float((unsigned)(p[q] & 0xFFFFFFFFull));
          mask &= ~(1u << q);
        }
      if (++guard > (1 << 14)) break;  // escape on protocol failure (no hang)
    }

    // ---- y_{t-1} = w_out . h_{t-1} (every WG computes; WG0 writes) ----
    float sy = 0.f;
    #pragma unroll
    for (int q = 0; q < 8; ++q) sy = fmaf(wo[q], hv[q], sy);
    #pragma unroll
    for (int off = 32; off >= 1; off >>= 1) sy += __shfl_xor(sy, off, 64);
    if (lane == 0) wys[wave] = sy;

    __syncthreads();  // sync A: polls done, wys ready, prev hs reads done

    if (t > 0 && tid == 0 && wg == 0)
      out[t - 1] = wys[0] + wys[1] + wys[2] + wys[3] + bout;

    if (t == SEQ) break;

    #pragma unroll
    for (int q = 0; q < 8; ++q) hs[tid + 256 * q] = hv[q];
    __syncthreads();  // sync B: hs ready

    // ---- z = W_hh @ h (per-lane partials over this lane's 32 columns) ----
    float acc[8] = {0.f, 0.f, 0.f, 0.f, 0.f, 0.f, 0.f, 0.f};
    #pragma unroll
    for (int j = 0; j < 8; ++j) {
      const float4 h4 = *(const float4*)&hs[j * 256 + lane * 4];
      #pragma unroll
      for (int m = 0; m < 8; ++m) {
        const float4 w = W[m * 8 + j];
        acc[m] = fmaf(w.x, h4.x, acc[m]);
        acc[m] = fmaf(w.y, h4.y, acc[m]);
        acc[m] = fmaf(w.z, h4.z, acc[m]);
        acc[m] = fmaf(w.w, h4.w, acc[m]);
      }
    }
    // ---- 64-lane butterfly reduce: all lanes end with full row sums ----
    #pragma unroll
    for (int off = 32; off >= 1; off >>= 1) {
      #pragma unroll
      for (int m = 0; m < 8; ++m)
        acc[m] += __shfl_xor(acc[m], off, 64);
    }

    const float xt = xs[t];
    float z[8];
    #pragma unroll
    for (int m = 0; m < 8; ++m) z[m] = fmaf(xt, wx[m], acc[m] + bb[m]);

    // ---- gates (redundant across lanes; identical values) ----
    {
      const float i0 = sigmoidf_(z[0]), f0 = sigmoidf_(z[1]);
      const float g0 = tanh_(z[2]), o0 = sigmoidf_(z[3]);
      c0 = f0 * c0 + i0 * g0;
      h0 = o0 * tanh_(c0);
      const float i1 = sigmoidf_(z[4]), f1 = sigmoidf_(z[5]);
      const float g1 = tanh_(z[6]), o1 = sigmoidf_(z[7]);
      c1 = f1 * c1 + i1 * g1;
      h1 = o1 * tanh_(c1);
    }

    // ---- publish h_t slice: (tag=t+1, value) pairs, slot t&1 ----
    if (lane == 0) {
      unsigned long long* dst = hbuf + (((unsigned)t & 1u) * HDIM);
      const unsigned long long tag = ((unsigned long long)(t + 1)) << 32;
      __hip_atomic_store(&dst[k0], tag | __float_as_uint(h0),
                         __ATOMIC_RELAXED, __HIP_MEMORY_SCOPE_AGENT);
      __hip_atomic_store(&dst[k1], tag | __float_as_uint(h1),
                         __ATOMIC_RELAXED, __HIP_MEMORY_SCOPE_AGENT);
    }
  }

  // ---- final h, c ----
  if (lane == 0) {
    out[SEQ + k0] = h0;
    out[SEQ + k1] = h1;
    out[SEQ + HDIM + k0] = c0;
    out[SEQ + HDIM + k1] = c1;
  }
}

extern "C" void kernel_launch(void* const* d_in, const int* in_sizes, int n_in,
                              void* d_out, int out_size, void* d_ws, size_t ws_size,
                              hipStream_t stream) {
  const float* x     = (const float*)d_in[0];
  const float* w_ih  = (const float*)d_in[1];
  const float* w_hh  = (const float*)d_in[2];
  const float* b_ih  = (const float*)d_in[3];
  const float* b_hh  = (const float*)d_in[4];
  const float* w_out = (const float*)d_in[5];
  const float* b_out = (const float*)d_in[6];
  float* out = (float*)d_out;

  // ws layout: [0, 32KB): hbuf = 2 slots x 2048 x 8B (tag,value) pairs
  unsigned long long* hbuf = (unsigned long long*)d_ws;

  lstm_init<<<8, 256, 0, stream>>>(hbuf);
  lstm_persist<<<NWG, TPB, 0, stream>>>(x, w_ih, w_hh, b_ih, b_hh, w_out,
                                        b_out, out, hbuf);
}

// Round 3
// 19199.724 us; speedup vs baseline: 1.3245x; 1.3245x over previous
//
#include <hip/hip_runtime.h>
#include <math.h>

// Persistent-kernel LSTM: H=2048, SEQ=4096, fp32 (no fp32 MFMA -> vector ALU).
// 256 WGs x 512 thr (8 waves), 1 WG/CU. Wave w of WG g owns hidden unit
// k = g*8+w; each lane holds 4 gate-rows x 32 cols of W_hh = 128 floats in
// VGPRs (no spill: ~195 regs, capped 256 via __launch_bounds__(512,2)).
// Per step: poll h_{t-1} (self-tagged 8B (tag,val) pairs, agent scope,
// s_sleep backoff), stage to double-buffered LDS (1 barrier/step), 128
// FMAs/lane, 64-lane butterfly, gates, publish unit. y is computed off the
// critical path after publish and drained with a 2-step delay by WG0.
// d_ws usage: 32 KB (hbuf double buffer).

#define HDIM 2048
#define SEQ 4096
#define NWG 256
#define TPB 512

__device__ __forceinline__ float sigmoidf_(float x) {
  return 1.0f / (1.0f + expf(-x));
}
__device__ __forceinline__ float tanh_(float x) {
  float e = expf(-2.0f * fabsf(x));
  float r = (1.0f - e) / (1.0f + e);
  return copysignf(r, x);
}

__global__ void lstm_init(unsigned long long* hbuf) {
  const int i = blockIdx.x * 256 + threadIdx.x;   // 2048 threads
  hbuf[HDIM + i] = 0ull;  // slot 1 = h_{-1}: value 0.0f, tag 0
}

__global__ __launch_bounds__(TPB, 2) void lstm_persist(
    const float* __restrict__ x, const float* __restrict__ w_ih,
    const float* __restrict__ w_hh, const float* __restrict__ b_ih,
    const float* __restrict__ b_hh, const float* __restrict__ w_out,
    const float* __restrict__ b_out, float* __restrict__ out,
    unsigned long long* hbuf)
{
  const int wg   = blockIdx.x;
  const int tid  = threadIdx.x;
  const int wave = tid >> 6;
  const int lane = tid & 63;
  const int k    = wg * 8 + wave;   // this wave's hidden unit

  __shared__ float xs[SEQ];        // 16 KB
  __shared__ float hs[2][HDIM];    // 16 KB, double-buffered
  __shared__ float wys[2][8];      // per-wave y partials, double-buffered

  // ---- one-time: weights into registers ----
  // rows g=0..3 (gates i,f,g,o of unit k): row = k + g*HDIM
  // cols per lane: {256*j + 4*lane + q}, j=0..7, q=0..3  -> 32 float4
  float4 W[32];
  float wx[4], bb[4];
  #pragma unroll
  for (int g = 0; g < 4; ++g) {
    const int row = k + g * HDIM;
    const float* rp = w_hh + (size_t)row * HDIM + lane * 4;
    #pragma unroll
    for (int j = 0; j < 8; ++j)
      W[g * 8 + j] = *(const float4*)(rp + j * 256);
    wx[g] = w_ih[row];
    bb[g] = b_ih[row] + b_hh[row];
  }
  float wo[4];
  #pragma unroll
  for (int q = 0; q < 4; ++q) wo[q] = w_out[tid + TPB * q];
  const float bout = b_out[0];

  for (int i = tid; i < SEQ; i += TPB) xs[i] = x[i];

  float cc = 0.f, hh = 0.f;
  __syncthreads();

  float hv[4];

  for (int t = 0; t < SEQ; ++t) {
    const int par = t & 1;
    // ---- poll h_{t-1}: want tag == t; lives in slot (t-1)&1 = par^1 ----
    unsigned long long* src = hbuf + ((unsigned)(par ^ 1)) * HDIM;
    unsigned long long p[4];
    #pragma unroll
    for (int q = 0; q < 4; ++q) hv[q] = 0.f;
    unsigned mask = 0xFu;
    int guard = 0;
    while (mask) {
      #pragma unroll
      for (int q = 0; q < 4; ++q)
        if (mask & (1u << q))
          p[q] = __hip_atomic_load(&src[tid + TPB * q], __ATOMIC_RELAXED,
                                   __HIP_MEMORY_SCOPE_AGENT);
      #pragma unroll
      for (int q = 0; q < 4; ++q)
        if ((mask & (1u << q)) && (unsigned)(p[q] >> 32) == (unsigned)t) {
          hv[q] = __uint_as_float((unsigned)(p[q] & 0xFFFFFFFFull));
          mask &= ~(1u << q);
        }
      if (mask) __builtin_amdgcn_s_sleep(2);   // back off: cut LLC poll storm
      if (++guard > (1 << 12)) break;          // protocol-failure escape
    }

    // ---- stage h to LDS (double buffer -> one barrier per step) ----
    #pragma unroll
    for (int q = 0; q < 4; ++q) hs[par][tid + TPB * q] = hv[q];
    __syncthreads();

    // ---- drain y_{t-2} (wys[par^1] written at step t-1, pre-barrier) ----
    if (t >= 2 && wg == 0 && tid == 0)
      out[t - 2] = wys[par ^ 1][0] + wys[par ^ 1][1] + wys[par ^ 1][2] +
                   wys[par ^ 1][3] + wys[par ^ 1][4] + wys[par ^ 1][5] +
                   wys[par ^ 1][6] + wys[par ^ 1][7] + bout;

    // ---- z = W_hh @ h (per-lane partials over 32 columns) ----
    float acc[4] = {0.f, 0.f, 0.f, 0.f};
    #pragma unroll
    for (int j = 0; j < 8; ++j) {
      const float4 h4 = *(const float4*)&hs[par][j * 256 + lane * 4];
      #pragma unroll
      for (int g = 0; g < 4; ++g) {
        const float4 w = W[g * 8 + j];
        acc[g] = fmaf(w.x, h4.x, acc[g]);
        acc[g] = fmaf(w.y, h4.y, acc[g]);
        acc[g] = fmaf(w.z, h4.z, acc[g]);
        acc[g] = fmaf(w.w, h4.w, acc[g]);
      }
    }
    // ---- 64-lane butterfly: all lanes end with full row sums ----
    #pragma unroll
    for (int off = 32; off >= 1; off >>= 1) {
      #pragma unroll
      for (int g = 0; g < 4; ++g)
        acc[g] += __shfl_xor(acc[g], off, 64);
    }

    const float xt = xs[t];
    float z[4];
    #pragma unroll
    for (int g = 0; g < 4; ++g) z[g] = fmaf(xt, wx[g], acc[g] + bb[g]);

    // ---- gates (lane-redundant, identical values) ----
    const float gi = sigmoidf_(z[0]), gf = sigmoidf_(z[1]);
    const float gg = tanh_(z[2]), go = sigmoidf_(z[3]);
    cc = gf * cc + gi * gg;
    hh = go * tanh_(cc);

    // ---- publish h_t: (tag=t+1, value) into slot t&1 — critical product ----
    if (lane == 0) {
      unsigned long long* dst = hbuf + ((unsigned)par) * HDIM;
      __hip_atomic_store(&dst[k],
                         (((unsigned long long)(t + 1)) << 32) |
                             __float_as_uint(hh),
                         __ATOMIC_RELAXED, __HIP_MEMORY_SCOPE_AGENT);
    }

    // ---- off-path: y_{t-1} partial from hv (h_{t-1}) ----
    float sy = 0.f;
    #pragma unroll
    for (int q = 0; q < 4; ++q) sy = fmaf(wo[q], hv[q], sy);
    #pragma unroll
    for (int off = 32; off >= 1; off >>= 1) sy += __shfl_xor(sy, off, 64);
    if (lane == 0) wys[par][wave] = sy;
  }

  // ---- epilogue: poll h_{SEQ-1} (tag SEQ, slot 1) for y_{SEQ-1} ----
  {
    unsigned long long* src = hbuf + HDIM;  // slot (SEQ-1)&1 = 1
    unsigned long long p[4];
    #pragma unroll
    for (int q = 0; q < 4; ++q) hv[q] = 0.f;
    unsigned mask = 0xFu;
    int guard = 0;
    while (mask) {
      #pragma unroll
      for (int q = 0; q < 4; ++q)
        if (mask & (1u << q))
          p[q] = __hip_atomic_load(&src[tid + TPB * q], __ATOMIC_RELAXED,
                                   __HIP_MEMORY_SCOPE_AGENT);
      #pragma unroll
      for (int q = 0; q < 4; ++q)
        if ((mask & (1u << q)) && (unsigned)(p[q] >> 32) == (unsigned)SEQ) {
          hv[q] = __uint_as_float((unsigned)(p[q] & 0xFFFFFFFFull));
          mask &= ~(1u << q);
        }
      if (mask) __builtin_amdgcn_s_sleep(2);
      if (++guard > (1 << 12)) break;
    }
  }
  __syncthreads();  // wys[(SEQ-1)&1] (= parity 1) complete

  if (wg == 0 && tid == 0)
    out[SEQ - 2] = wys[1][0] + wys[1][1] + wys[1][2] + wys[1][3] + wys[1][4] +
                   wys[1][5] + wys[1][6] + wys[1][7] + bout;

  float sy = 0.f;
  #pragma unroll
  for (int q = 0; q < 4; ++q) sy = fmaf(wo[q], hv[q], sy);
  #pragma unroll
  for (int off = 32; off >= 1; off >>= 1) sy += __shfl_xor(sy, off, 64);
  if (lane == 0) wys[0][wave] = sy;
  __syncthreads();
  if (wg == 0 && tid == 0)
    out[SEQ - 1] = wys[0][0] + wys[0][1] + wys[0][2] + wys[0][3] + wys[0][4] +
                   wys[0][5] + wys[0][6] + wys[0][7] + bout;

  // ---- final h, c ----
  if (lane == 0) {
    out[SEQ + k] = hh;
    out[SEQ + HDIM + k] = cc;
  }
}

extern "C" void kernel_launch(void* const* d_in, const int* in_sizes, int n_in,
                              void* d_out, int out_size, void* d_ws, size_t ws_size,
                              hipStream_t stream) {
  const float* x     = (const float*)d_in[0];
  const float* w_ih  = (const float*)d_in[1];
  const float* w_hh  = (const float*)d_in[2];
  const float* b_ih  = (const float*)d_in[3];
  const float* b_hh  = (const float*)d_in[4];
  const float* w_out = (const float*)d_in[5];
  const float* b_out = (const float*)d_in[6];
  float* out = (float*)d_out;

  // ws layout: [0, 32KB): hbuf = 2 slots x 2048 x 8B (tag,value) pairs
  unsigned long long* hbuf = (unsigned long long*)d_ws;

  lstm_init<<<8, 256, 0, stream>>>(hbuf);
  lstm_persist<<<NWG, TPB, 0, stream>>>(x, w_ih, w_hh, b_ih, b_hh, w_out,
                                        b_out, out, hbuf);
}

// Round 4
// 12010.040 us; speedup vs baseline: 2.1174x; 1.5986x over previous
//
#include <hip/hip_runtime.h>
#include <math.h>

// Persistent-kernel LSTM: H=2048, SEQ=4096, fp32 (no fp32 MFMA -> vector ALU).
// 256 WGs x 512 thr, 1 WG/CU. Wave w of WG g owns hidden unit k=g*8+w; each
// lane holds 4 gate-rows x 32 cols of W_hh (128 floats, VGPR+AGPR unified).
// Cross-step exchange v2 (anti poll-storm):
//   data:  float hval[2][2048]  (relaxed agent stores, sc1 -> LLC)
//   ready: uint  flags[2][256]  (per-WG flag = t+1, stored by tid0 AFTER
//          __syncthreads drains all waves' data stores to the LLC)
//   consumer: wave 0 only polls all 256 flags (4 coalesced loads/sweep),
//          then one barrier, then each thread loads its 4 h values ONCE.
// y is computed off-path from the already-loaded hv and drained with a
// 2-step delay by WG0. d_ws usage: 18 KB.

#define HDIM 2048
#define SEQ 4096
#define NWG 256
#define TPB 512

__device__ __forceinline__ float sigmoidf_(float x) {
  return 1.0f / (1.0f + expf(-x));
}
__device__ __forceinline__ float tanh_(float x) {
  float e = expf(-2.0f * fabsf(x));
  float r = (1.0f - e) / (1.0f + e);
  return copysignf(r, x);
}

// zero slot-1 values and slot-1 flags (what step t=0 consumes)
__global__ void lstm_init(float* hval, unsigned* flags) {
  const int i = blockIdx.x * 256 + threadIdx.x;   // 8 blocks x 256 = 2048
  hval[HDIM + i] = 0.f;
  if (i < NWG) flags[NWG + i] = 0u;
}

__global__ __launch_bounds__(TPB, 2) void lstm_persist(
    const float* __restrict__ x, const float* __restrict__ w_ih,
    const float* __restrict__ w_hh, const float* __restrict__ b_ih,
    const float* __restrict__ b_hh, const float* __restrict__ w_out,
    const float* __restrict__ b_out, float* __restrict__ out,
    float* __restrict__ hval, unsigned* __restrict__ flags)
{
  const int wg   = blockIdx.x;
  const int tid  = threadIdx.x;
  const int wave = tid >> 6;
  const int lane = tid & 63;
  const int k    = wg * 8 + wave;   // this wave's hidden unit

  __shared__ float xs[SEQ];        // 16 KB
  __shared__ float hs[2][HDIM];    // 16 KB, double-buffered
  __shared__ float wys[2][8];      // per-wave y partials, double-buffered

  // ---- one-time: weights into registers ----
  // rows g=0..3 (gates i,f,g,o of unit k): row = k + g*HDIM
  // cols per lane: {256*j + 4*lane + q}, j=0..7, q=0..3  -> 32 float4
  float4 W[32];
  float wx[4], bb[4];
  #pragma unroll
  for (int g = 0; g < 4; ++g) {
    const int row = k + g * HDIM;
    const float* rp = w_hh + (size_t)row * HDIM + lane * 4;
    #pragma unroll
    for (int j = 0; j < 8; ++j)
      W[g * 8 + j] = *(const float4*)(rp + j * 256);
    wx[g] = w_ih[row];
    bb[g] = b_ih[row] + b_hh[row];
  }
  float wo[4];
  #pragma unroll
  for (int q = 0; q < 4; ++q) wo[q] = w_out[tid + TPB * q];
  const float bout = b_out[0];

  for (int i = tid; i < SEQ; i += TPB) xs[i] = x[i];

  float cc = 0.f, hh = 0.f;
  float hv[4];
  __syncthreads();

  for (int t = 0; t < SEQ; ++t) {
    const int par = t & 1;

    // ---- scout: wave 0 polls all 256 flags of slot par^1 for value t ----
    if (wave == 0) {
      const unsigned* f = flags + (par ^ 1) * NWG;
      int guard = 0;
      for (;;) {
        const unsigned f0 = __hip_atomic_load(&f[lane], __ATOMIC_RELAXED,
                                              __HIP_MEMORY_SCOPE_AGENT);
        const unsigned f1 = __hip_atomic_load(&f[lane + 64], __ATOMIC_RELAXED,
                                              __HIP_MEMORY_SCOPE_AGENT);
        const unsigned f2 = __hip_atomic_load(&f[lane + 128], __ATOMIC_RELAXED,
                                              __HIP_MEMORY_SCOPE_AGENT);
        const unsigned f3 = __hip_atomic_load(&f[lane + 192], __ATOMIC_RELAXED,
                                              __HIP_MEMORY_SCOPE_AGENT);
        const int ok = (f0 == (unsigned)t) & (f1 == (unsigned)t) &
                       (f2 == (unsigned)t) & (f3 == (unsigned)t);
        if (__all(ok)) break;
        if (++guard > 2048) break;   // protocol-failure escape (no hang)
      }
    }
    __syncthreads();  // B1: h_{t-1} fully published at the LLC

    // ---- load h_{t-1} ONCE (sc1 -> LLC), stage to LDS ----
    const float* hsrc = hval + (par ^ 1) * HDIM;
    #pragma unroll
    for (int q = 0; q < 4; ++q)
      hv[q] = __hip_atomic_load(&hsrc[tid + TPB * q], __ATOMIC_RELAXED,
                                __HIP_MEMORY_SCOPE_AGENT);
    #pragma unroll
    for (int q = 0; q < 4; ++q) hs[par][tid + TPB * q] = hv[q];
    __syncthreads();  // B2: hs ready (also: wys[par^1] stable to read)

    // ---- drain y_{t-2} (wys[par^1] written at step t-1) ----
    if (t >= 2 && wg == 0 && tid == 0)
      out[t - 2] = wys[par ^ 1][0] + wys[par ^ 1][1] + wys[par ^ 1][2] +
                   wys[par ^ 1][3] + wys[par ^ 1][4] + wys[par ^ 1][5] +
                   wys[par ^ 1][6] + wys[par ^ 1][7] + bout;

    // ---- z = W_hh @ h (per-lane partials over 32 columns) ----
    float acc[4] = {0.f, 0.f, 0.f, 0.f};
    #pragma unroll
    for (int j = 0; j < 8; ++j) {
      const float4 h4 = *(const float4*)&hs[par][j * 256 + lane * 4];
      #pragma unroll
      for (int g = 0; g < 4; ++g) {
        const float4 w = W[g * 8 + j];
        acc[g] = fmaf(w.x, h4.x, acc[g]);
        acc[g] = fmaf(w.y, h4.y, acc[g]);
        acc[g] = fmaf(w.z, h4.z, acc[g]);
        acc[g] = fmaf(w.w, h4.w, acc[g]);
      }
    }
    // ---- 64-lane butterfly: all lanes end with full row sums ----
    #pragma unroll
    for (int off = 32; off >= 1; off >>= 1) {
      #pragma unroll
      for (int g = 0; g < 4; ++g)
        acc[g] += __shfl_xor(acc[g], off, 64);
    }

    const float xt = xs[t];
    float z[4];
    #pragma unroll
    for (int g = 0; g < 4; ++g) z[g] = fmaf(xt, wx[g], acc[g] + bb[g]);

    // ---- gates (lane-redundant, identical values) ----
    const float gi = sigmoidf_(z[0]), gf = sigmoidf_(z[1]);
    const float gg = tanh_(z[2]), go = sigmoidf_(z[3]);
    cc = gf * cc + gi * gg;
    hh = go * tanh_(cc);

    // ---- publish h_t ----
    if (lane == 0)
      __hip_atomic_store(&hval[par * HDIM + k], hh, __ATOMIC_RELAXED,
                         __HIP_MEMORY_SCOPE_AGENT);
    __syncthreads();  // B3: drains ALL waves' data stores (vmcnt(0) -> LLC)
    if (tid == 0)
      __hip_atomic_store(&flags[par * NWG + wg], (unsigned)(t + 1),
                         __ATOMIC_RELAXED, __HIP_MEMORY_SCOPE_AGENT);

    // ---- off-path: y_{t-1} partial from hv (h_{t-1}) ----
    float sy = 0.f;
    #pragma unroll
    for (int q = 0; q < 4; ++q) sy = fmaf(wo[q], hv[q], sy);
    #pragma unroll
    for (int off = 32; off >= 1; off >>= 1) sy += __shfl_xor(sy, off, 64);
    if (lane == 0) wys[par][wave] = sy;
  }

  // ---- epilogue ----
  __syncthreads();  // wys[1] (y partial for h_{SEQ-2}) complete
  if (wg == 0 && tid == 0)
    out[SEQ - 2] = wys[1][0] + wys[1][1] + wys[1][2] + wys[1][3] + wys[1][4] +
                   wys[1][5] + wys[1][6] + wys[1][7] + bout;

  if (wg == 0) {
    // poll flags slot1 == SEQ, then y_{SEQ-1} = w_out . h_{SEQ-1}
    if (wave == 0) {
      const unsigned* f = flags + NWG;  // slot (SEQ-1)&1 = 1
      int guard = 0;
      for (;;) {
        const unsigned f0 = __hip_atomic_load(&f[lane], __ATOMIC_RELAXED,
                                              __HIP_MEMORY_SCOPE_AGENT);
        const unsigned f1 = __hip_atomic_load(&f[lane + 64], __ATOMIC_RELAXED,
                                              __HIP_MEMORY_SCOPE_AGENT);
        const unsigned f2 = __hip_atomic_load(&f[lane + 128], __ATOMIC_RELAXED,
                                              __HIP_MEMORY_SCOPE_AGENT);
        const unsigned f3 = __hip_atomic_load(&f[lane + 192], __ATOMIC_RELAXED,
                                              __HIP_MEMORY_SCOPE_AGENT);
        const int ok = (f0 == (unsigned)SEQ) & (f1 == (unsigned)SEQ) &
                       (f2 == (unsigned)SEQ) & (f3 == (unsigned)SEQ);
        if (__all(ok)) break;
        if (++guard > 2048) break;
      }
    }
    __syncthreads();
    float sy = 0.f;
    #pragma unroll
    for (int q = 0; q < 4; ++q) {
      const float hq = __hip_atomic_load(&hval[HDIM + tid + TPB * q],
                                         __ATOMIC_RELAXED,
                                         __HIP_MEMORY_SCOPE_AGENT);
      sy = fmaf(wo[q], hq, sy);
    }
    #pragma unroll
    for (int off = 32; off >= 1; off >>= 1) sy += __shfl_xor(sy, off, 64);
    if (lane == 0) wys[0][wave] = sy;
    __syncthreads();
    if (tid == 0)
      out[SEQ - 1] = wys[0][0] + wys[0][1] + wys[0][2] + wys[0][3] +
                     wys[0][4] + wys[0][5] + wys[0][6] + wys[0][7] + bout;
  }

  // ---- final h, c ----
  if (lane == 0) {
    out[SEQ + k] = hh;
    out[SEQ + HDIM + k] = cc;
  }
}

extern "C" void kernel_launch(void* const* d_in, const int* in_sizes, int n_in,
                              void* d_out, int out_size, void* d_ws, size_t ws_size,
                              hipStream_t stream) {
  const float* x     = (const float*)d_in[0];
  const float* w_ih  = (const float*)d_in[1];
  const float* w_hh  = (const float*)d_in[2];
  const float* b_ih  = (const float*)d_in[3];
  const float* b_hh  = (const float*)d_in[4];
  const float* w_out = (const float*)d_in[5];
  const float* b_out = (const float*)d_in[6];
  float* out = (float*)d_out;

  // ws layout: [0,16KB): hval[2][2048] float; [16KB,18KB): flags[2][256] uint
  float* hval = (float*)d_ws;
  unsigned* flags = (unsigned*)((char*)d_ws + 16 * 1024);

  lstm_init<<<8, 256, 0, stream>>>(hval, flags);
  lstm_persist<<<NWG, TPB, 0, stream>>>(x, w_ih, w_hh, b_ih, b_hh, w_out,
                                        b_out, out, hval, flags);
}